// Round 6
// baseline (111.225 us; speedup 1.0000x reference)
//
#include <hip/hip_runtime.h>

// Problem constants: N_SUPPORT=10, N_QUERY=25, N_CLASS=2
// ns_all = 20, nq_all = 50, D = 128, F = 512
#define NS_ALL 20
#define NQ_ALL 50
#define DIM0   128
#define F4     128   // float4 per input row (512 floats)

// Output (f4 units): flat = (pair*128 + d)*256 + c4,  pair = q*20+s, c4 in [0,256)
//   c4 in [0,128)   : sup[s,d,:]
//   c4 in [128,256) : qry[q,d,:]
//
// R6: register-source scatter. One block = one input half-row (2 KB) held in
// registers (128 thr x f32x4); emit 50 (sup) / 20 (qry) dependency-free nt
// stores. No LDS, no syncthreads, no lgkmcnt in the store loop; each input
// byte read exactly once (reads 51 MB -> 18 MB). Maximally fill-like stores.

typedef float f32x4 __attribute__((ext_vector_type(4)));

#define SUP_BLOCKS (NS_ALL * DIM0)   // 2560
#define QRY_BLOCKS (NQ_ALL * DIM0)   // 6400

__global__ __launch_bounds__(128) void concat_scatter_kernel(
    const f32x4* __restrict__ x4, f32x4* __restrict__ out4)
{
    const int tid = threadIdx.x;                 // 0..127
    const int bid = blockIdx.x;
    const f32x4* sup4 = x4;                      // 20*128*128 f4
    const f32x4* qry4 = x4 + NS_ALL * DIM0 * F4; // + 327680

    if (bid < SUP_BLOCKS) {
        // sup block: owns sup[s,d,:]; writes it to all q
        const int s = bid >> 7;
        const int d = bid & 127;
        const f32x4 v = sup4[((s << 7) + d) * F4 + tid];
        // q=0 address; per-q stride = 20*128*256 f4 = 655360
        int idx = (((s << 7) + d) << 8) + tid;
        #pragma unroll
        for (int q = 0; q < NQ_ALL; ++q) {
            __builtin_nontemporal_store(v, &out4[idx]);
            idx += NS_ALL * DIM0 * 256;
        }
    } else {
        // qry block: owns qry[q,d,:]; writes it to all s
        const int b = bid - SUP_BLOCKS;
        const int q = b >> 7;
        const int d = b & 127;
        const f32x4 v = qry4[((q << 7) + d) * F4 + tid];
        // s=0 address (second half-row); per-s stride = 128*256 f4 = 32768
        int idx = ((q * (NS_ALL * DIM0) + d) << 8) + F4 + tid;
        #pragma unroll
        for (int s = 0; s < NS_ALL; ++s) {
            __builtin_nontemporal_store(v, &out4[idx]);
            idx += DIM0 * 256;
        }
    }
}

extern "C" void kernel_launch(void* const* d_in, const int* in_sizes, int n_in,
                              void* d_out, int out_size, void* d_ws, size_t ws_size,
                              hipStream_t stream) {
    const f32x4* x4 = (const f32x4*)d_in[0];
    f32x4* out4 = (f32x4*)d_out;

    const int threads = 128;
    const int blocks = SUP_BLOCKS + QRY_BLOCKS;   // 8960
    concat_scatter_kernel<<<blocks, threads, 0, stream>>>(x4, out4);
}

// Round 7
// 91.429 us; speedup vs baseline: 1.2165x; 1.2165x over previous
//
#include <hip/hip_runtime.h>

// Problem constants: N_SUPPORT=10, N_QUERY=25, N_CLASS=2
// ns_all = 20, nq_all = 50, D = 128, F = 512
#define NS_ALL 20
#define NQ_ALL 50
#define DIM0   128
#define FEAT   512

// Output: (50*20, 128, 1024) fp32.  out[q,s,d,0:512]=sup[s,d,:], [512:1024]=qry[q,d,:]
//
// R7: R4 (LDS tile (10,10), nt stores, d-fastest block order) with the stage
// phase converted to async global_load_lds (width=16): 10 wave-issues,
// no VGPR round-trip, drained once by __syncthreads. Single-variable A/B
// vs R4's load->ds_write stage.

typedef float f32x4 __attribute__((ext_vector_type(4)));

#define QT 10           // q's per block
#define ST 10           // s's per block
#define F4 (FEAT / 4)   // 128 float4 per input row
#define LDS_F4 ((QT + ST) * F4)   // 2560 f4 = 40 KB

__global__ __launch_bounds__(256) void concat_pairs_lds_kernel(
    const f32x4* __restrict__ x4, f32x4* __restrict__ out4)
{
    const f32x4* sup4 = x4;                              // 20*128*128 f4
    const f32x4* qry4 = x4 + NS_ALL * DIM0 * F4;         // + 327680

    __shared__ f32x4 lds[LDS_F4];                        // 40 KB

    const int tid = threadIdx.x;
    const int bid = blockIdx.x;          // (qt*2+st)*128 + d, d fastest
    const int d   = bid & 127;
    const int tb  = bid >> 7;            // 0..9
    const int st  = tb & 1;              // 0..1
    const int qt  = tb >> 1;             // 0..4

    // ---- stage phase: 2560 f4 via async global_load_lds (10 wave-issues) ----
    #pragma unroll
    for (int k = 0; k < LDS_F4 / 256; ++k) {
        int j = k * 256 + tid;           // lane-contiguous per wave
        const f32x4* src;
        if (j < ST * F4) {
            int s   = j >> 7;
            int off = j & 127;
            src = &sup4[((st * ST + s) * DIM0 + d) * F4 + off];
        } else {
            int jj  = j - ST * F4;
            int q   = jj >> 7;
            int off = jj & 127;
            src = &qry4[((qt * QT + q) * DIM0 + d) * F4 + off];
        }
        __builtin_amdgcn_global_load_lds(
            (const __attribute__((address_space(1))) unsigned int*)src,
            (__attribute__((address_space(3))) unsigned int*)&lds[j],
            16, 0, 0);
    }
    __syncthreads();   // drains vmcnt + barrier

    // ---- emit phase: 100 output rows of 256 f4 each ----
    const f32x4* src = (tid < F4) ? &lds[tid] : &lds[ST * F4 + (tid - F4)];
    #pragma unroll
    for (int r = 0; r < QT * ST; ++r) {
        int q = r / ST;                // 0..9
        int s = r - q * ST;            // 0..9
        f32x4 v = (tid < F4) ? src[s * F4] : src[q * F4];
        int pair = (qt * QT + q) * NS_ALL + (st * ST + s);
        __builtin_nontemporal_store(v, &out4[((pair << 7) + d) * 256 + tid]);
    }
}

extern "C" void kernel_launch(void* const* d_in, const int* in_sizes, int n_in,
                              void* d_out, int out_size, void* d_ws, size_t ws_size,
                              hipStream_t stream) {
    const f32x4* x4 = (const f32x4*)d_in[0];
    f32x4* out4 = (f32x4*)d_out;

    const int threads = 256;
    const int blocks = (NQ_ALL / QT) * (NS_ALL / ST) * DIM0;  // 5*2*128 = 1280
    concat_pairs_lds_kernel<<<blocks, threads, 0, stream>>>(x4, out4);
}

// Round 8
// 90.703 us; speedup vs baseline: 1.2263x; 1.0080x over previous
//
#include <hip/hip_runtime.h>

// Problem constants: N_SUPPORT=10, N_QUERY=25, N_CLASS=2
// ns_all = 20, nq_all = 50, D = 128, F = 512
#define NS_ALL 20
#define NQ_ALL 50
#define DIM0   128
#define FEAT   512

// Output: (50*20, 128, 1024) fp32.  out[q,s,d,0:512]=sup[s,d,:], [512:1024]=qry[q,d,:]
//
// FINAL (R8 = R4 restored, best-known 88.8-89.0 us = 5.9 TB/s effective):
//  - LDS tile (QT,ST)=(10,10): stage 20 input half-rows (40 KB) once,
//    emit 100 output rows from LDS. 4 blocks/CU, 16 waves/CU.
//  - d-fastest block order: 128-block cohorts write adjacent 4 KB rows
//    (dense 512 KB stripes) — R6 showed sparse per-wave streams cost 25%.
//  - nontemporal stores: R5 showed plain (write-allocate) stores cost 14%.
//  - plain per-thread stage loads: R7 showed async global_load_lds is -3%.
// Probed and rejected: MLP unroll (R2), lower read volume (R4), plain
// stores (R5), register scatter (R6), async stage (R7). Residual vs the
// 6.87 TB/s pure-write fill rate is the read-stream/write-stream fabric
// co-schedule — structural for an op that must read everything it writes.

typedef float f32x4 __attribute__((ext_vector_type(4)));

#define QT 10           // q's per block
#define ST 10           // s's per block
#define F4 (FEAT / 4)   // 128 float4 per input row
#define LDS_F4 ((QT + ST) * F4)   // 2560 f4 = 40 KB

__global__ __launch_bounds__(256) void concat_pairs_lds_kernel(
    const f32x4* __restrict__ x4, f32x4* __restrict__ out4)
{
    const f32x4* sup4 = x4;                              // 20*128*128 f4
    const f32x4* qry4 = x4 + NS_ALL * DIM0 * F4;         // + 327680

    __shared__ f32x4 lds[LDS_F4];                        // 40 KB

    const int tid = threadIdx.x;
    const int bid = blockIdx.x;          // (qt*2+st)*128 + d, d fastest
    const int d   = bid & 127;
    const int tb  = bid >> 7;            // 0..9
    const int st  = tb & 1;              // 0..1
    const int qt  = tb >> 1;             // 0..4

    // ---- stage phase: 2560 f4 = ST sup rows + QT qry rows ----
    for (int j = tid; j < LDS_F4; j += 256) {
        f32x4 v;
        if (j < ST * F4) {
            int s   = j >> 7;
            int off = j & 127;
            v = sup4[((st * ST + s) * DIM0 + d) * F4 + off];
        } else {
            int jj  = j - ST * F4;
            int q   = jj >> 7;
            int off = jj & 127;
            v = qry4[((qt * QT + q) * DIM0 + d) * F4 + off];
        }
        lds[j] = v;
    }
    __syncthreads();

    // ---- emit phase: QT*ST = 100 output rows of 256 f4 each ----
    const f32x4* src = (tid < F4) ? &lds[tid] : &lds[ST * F4 + (tid - F4)];
    #pragma unroll
    for (int r = 0; r < QT * ST; ++r) {
        int q = r / ST;                // 0..9
        int s = r - q * ST;            // 0..9
        f32x4 v = (tid < F4) ? src[s * F4] : src[q * F4];
        int pair = (qt * QT + q) * NS_ALL + (st * ST + s);
        __builtin_nontemporal_store(v, &out4[((pair << 7) + d) * 256 + tid]);
    }
}

extern "C" void kernel_launch(void* const* d_in, const int* in_sizes, int n_in,
                              void* d_out, int out_size, void* d_ws, size_t ws_size,
                              hipStream_t stream) {
    const f32x4* x4 = (const f32x4*)d_in[0];
    f32x4* out4 = (f32x4*)d_out;

    const int threads = 256;
    const int blocks = (NQ_ALL / QT) * (NS_ALL / ST) * DIM0;  // 5*2*128 = 1280
    concat_pairs_lds_kernel<<<blocks, threads, 0, stream>>>(x4, out4);
}